// Round 7
// baseline (55.427 us; speedup 1.0000x reference)
//
#include <hip/hip_runtime.h>

namespace {

constexpr int F   = 128;
constexpr int L   = 4096;
constexpr int Bsz = 32;
constexpr int NT  = 8;     // n-tiles of 16 (128 cols)

using short8 = __attribute__((ext_vector_type(8))) short;
using f32x4  = __attribute__((ext_vector_type(4))) float;
using u32x4  = __attribute__((ext_vector_type(4))) unsigned int;

__device__ inline unsigned short f2bf(float x) {
    unsigned u = __builtin_bit_cast(unsigned, x);
    unsigned r = (u + 0x7fffu + ((u >> 16) & 1u)) >> 16;
    return (unsigned short)r;
}

__device__ inline unsigned pack2(float lo, float hi) {
    return (unsigned)f2bf(lo) | ((unsigned)f2bf(hi) << 16);
}

__device__ inline short8 cvt8(float4 a, float4 b) {
    u32x4 u;
    u[0] = pack2(a.x, a.y);
    u[1] = pack2(a.z, a.w);
    u[2] = pack2(b.x, b.y);
    u[3] = pack2(b.z, b.w);
    return __builtin_bit_cast(short8, u);
}

// Head-folded weights in MFMA-A-fragment order (one (s,tn) fragment read is
// 64 CONSECUTIVE 16B chunks -> lane-linear, coalesced):
//   bf16 idx: j = idx&7, chunk c2 = idx>>3
//   l15 = c2&15, g = (c2>>4)&3, tn = (c2>>6)&7, s = c2>>9
//   n = tn*16 + l15,  k = (s*4+g)*8 + j
//   k<128: mean_h W_src[(h*128+n)*128+k]; k>=128: mean_h W_res[...][k-128]
__global__ void prep(const float* __restrict__ Wsrc,
                     const float* __restrict__ Wres,
                     const float* __restrict__ bias,
                     unsigned short* __restrict__ Wf,
                     float* __restrict__ bbar)
{
    int idx = blockIdx.x * 256 + threadIdx.x;
    if (idx < 2 * F * F) {
        int j   = idx & 7;
        int c2  = idx >> 3;
        int l15 = c2 & 15;
        int g   = (c2 >> 4) & 3;
        int tn  = (c2 >> 6) & 7;
        int s   = c2 >> 9;
        int n   = tn * 16 + l15;
        int k   = (s * 4 + g) * 8 + j;
        int e   = k & (F - 1);
        const float* W = (k < F) ? Wsrc : Wres;
        float sum = 0.f;
#pragma unroll
        for (int h = 0; h < 8; ++h) sum += W[(h * F + n) * F + e];
        Wf[idx] = f2bf(sum * 0.125f);
    }
    if (idx < F) {
        float s = 0.f;
#pragma unroll
        for (int h = 0; h < 8; ++h) s += bias[h * F + idx];
        bbar[idx] = s * 0.125f;
    }
}

// One wave = one 16-row group. No LDS, no barriers: B-fragments are read
// straight from global (L2/L3-resident 64 KB, shared by all waves).
__global__ __launch_bounds__(256, 4)
void gat_mfma(const float* __restrict__ loc,
              const unsigned short* __restrict__ Wf,
              const float* __restrict__ bbar,
              float* __restrict__ out)
{
    const int t    = threadIdx.x;
    const int lane = t & 63;
    const int w    = t >> 6;
    const int g    = lane >> 4;
    const int l15  = lane & 15;

    const int rg = blockIdx.x * 4 + w;     // row-group 0..8191
    const int R  = rg * 16 + l15;          // global row (b*L + p)
    const int p  = R & (L - 1);            // row within batch (groups never straddle b)

    const int coff = g * 8;
    const float* curp  = loc + (size_t)R * F + coff;
    const float* prevp = (p == 0) ? curp : curp - F;

    // ---- A: 16 x dwordx4 global loads, convert to bf16 fragments
    float4 P[8], C[8];
#pragma unroll
    for (int s = 0; s < 4; ++s) {
        P[s * 2]     = *(const float4*)(prevp + s * 32);
        P[s * 2 + 1] = *(const float4*)(prevp + s * 32 + 4);
        C[s * 2]     = *(const float4*)(curp + s * 32);
        C[s * 2 + 1] = *(const float4*)(curp + s * 32 + 4);
    }
    short8 afr[8];
#pragma unroll
    for (int s = 0; s < 4; ++s) {
        afr[s]     = cvt8(P[s * 2], P[s * 2 + 1]);
        afr[s + 4] = cvt8(C[s * 2], C[s * 2 + 1]);
    }

    f32x4 acc[NT];
#pragma unroll
    for (int i = 0; i < NT; ++i) { acc[i][0] = 0.f; acc[i][1] = 0.f; acc[i][2] = 0.f; acc[i][3] = 0.f; }

    // ---- B from global: 64 lane-linear 1KB fragment reads (L1/L2 hits)
    const char* wbase = (const char*)Wf + lane * 16;
#pragma unroll
    for (int s = 0; s < 8; ++s) {
#pragma unroll
        for (int tn = 0; tn < NT; ++tn) {
            short8 wfrag = *(const short8*)(wbase + ((s * NT + tn) << 10));
            acc[tn] = __builtin_amdgcn_mfma_f32_16x16x32_bf16(wfrag, afr[s], acc[tn], 0, 0, 0);
        }
    }

    // ---- epilogue: lane holds cols (tn*16 + g*4 + r) of row R
    float* outr = out + (size_t)R * F;
    const float* row0 = curp - coff;   // when p==0, curp is row 0 of batch b
#pragma unroll
    for (int tn = 0; tn < NT; ++tn) {
        int col = tn * 16 + g * 4;
        float4 bb = *(const float4*)(bbar + col);
        float4 v = make_float4(acc[tn][0] + bb.x, acc[tn][1] + bb.y,
                               acc[tn][2] + bb.z, acc[tn][3] + bb.w);
        if (p == 0) v = *(const float4*)(row0 + col);   // out[b,0,:] = loc[b,0,:]
        *(float4*)(outr + col) = v;
    }
}

} // namespace

extern "C" void kernel_launch(void* const* d_in, const int* in_sizes, int n_in,
                              void* d_out, int out_size, void* d_ws, size_t ws_size,
                              hipStream_t stream) {
    const float* loc  = (const float*)d_in[0];
    const float* Wsrc = (const float*)d_in[1];
    // d_in[2] W_dst, d_in[3] attn_l, d_in[4] attn_r cancel (alpha == 1)
    const float* Wres = (const float*)d_in[5];
    const float* bias = (const float*)d_in[6];

    unsigned short* Wf   = (unsigned short*)d_ws;          // 32768 bf16 = 64 KB
    float*          bbar = (float*)((char*)d_ws + 2 * F * F * 2);
    float*          outp = (float*)d_out;

    prep<<<128, 256, 0, stream>>>(Wsrc, Wres, bias, Wf, bbar);

    // 8192 row-groups, 4 waves per 256-thread block
    gat_mfma<<<2048, 256, 0, stream>>>(loc, Wf, bbar, outp);
}

// Round 8
// 42.439 us; speedup vs baseline: 1.3061x; 1.3061x over previous
//
#include <hip/hip_runtime.h>

namespace {

constexpr int F   = 128;
constexpr int L   = 4096;
constexpr int NT  = 8;     // n-tiles of 16 (128 cols)

using short8 = __attribute__((ext_vector_type(8))) short;
using f32x4  = __attribute__((ext_vector_type(4))) float;
using u32x4  = __attribute__((ext_vector_type(4))) unsigned int;

__device__ inline unsigned short f2bf(float x) {
    unsigned u = __builtin_bit_cast(unsigned, x);
    unsigned r = (u + 0x7fffu + ((u >> 16) & 1u)) >> 16;
    return (unsigned short)r;
}

__device__ inline unsigned pack2(float lo, float hi) {
    return (unsigned)f2bf(lo) | ((unsigned)f2bf(hi) << 16);
}

__device__ inline short8 cvt8(float4 a, float4 b) {
    u32x4 u;
    u[0] = pack2(a.x, a.y);
    u[1] = pack2(a.z, a.w);
    u[2] = pack2(b.x, b.y);
    u[3] = pack2(b.z, b.w);
    return __builtin_bit_cast(short8, u);
}

// Head-folded weights in MFMA-A-fragment order (one (s,tn) fragment read is
// 64 CONSECUTIVE 16B chunks -> lane-linear, conflict-free):
//   bf16 idx: j = idx&7, chunk c2 = idx>>3
//   l15 = c2&15, g = (c2>>4)&3, tn = (c2>>6)&7, s = c2>>9
//   n = tn*16 + l15,  k = (s*4+g)*8 + j
//   k<128: mean_h W_src[(h*128+n)*128+k]; k>=128: mean_h W_res[...][k-128]
__global__ void prep(const float* __restrict__ Wsrc,
                     const float* __restrict__ Wres,
                     const float* __restrict__ bias,
                     unsigned short* __restrict__ Wf,
                     float* __restrict__ bbar)
{
    int idx = blockIdx.x * 256 + threadIdx.x;
    if (idx < 2 * F * F) {
        int j   = idx & 7;
        int c2  = idx >> 3;
        int l15 = c2 & 15;
        int g   = (c2 >> 4) & 3;
        int tn  = (c2 >> 6) & 7;
        int s   = c2 >> 9;
        int n   = tn * 16 + l15;
        int k   = (s * 4 + g) * 8 + j;
        int e   = k & (F - 1);
        const float* W = (k < F) ? Wsrc : Wres;
        float sum = 0.f;
#pragma unroll
        for (int h = 0; h < 8; ++h) sum += W[(h * F + n) * F + e];
        Wf[idx] = f2bf(sum * 0.125f);
    }
    if (idx < F) {
        float s = 0.f;
#pragma unroll
        for (int h = 0; h < 8; ++h) s += bias[h * F + idx];
        bbar[idx] = s * 0.125f;
    }
}

// Persistent: 512 blocks (2/CU), 4 waves each. B staged to LDS once; 4
// tile-steps of 64 rows with register double-buffered A prefetch.

// Issue the 16 A loads for step `ITC` into buffers Pb/Cb (prev-row / cur-row)
#define LOADA(ITC, Pb, Cb)                                                   \
    {                                                                        \
        int R_  = (bx + (ITC) * 512) * 64 + w * 16 + l15;                    \
        int p_  = R_ & (L - 1);                                              \
        const float* cc_ = loc + (size_t)R_ * F + coff;                      \
        const float* pp_ = (p_ == 0) ? cc_ : cc_ - F;                        \
        _Pragma("unroll")                                                    \
        for (int q = 0; q < 4; ++q) {                                        \
            Pb[q * 2]     = *(const float4*)(pp_ + q * 32);                  \
            Pb[q * 2 + 1] = *(const float4*)(pp_ + q * 32 + 4);              \
            Cb[q * 2]     = *(const float4*)(cc_ + q * 32);                  \
            Cb[q * 2 + 1] = *(const float4*)(cc_ + q * 32 + 4);              \
        }                                                                    \
    }

__global__ __launch_bounds__(256, 2)
void gat_mfma(const float* __restrict__ loc,
              const unsigned short* __restrict__ Wf,
              const float* __restrict__ bbar,
              float* __restrict__ out)
{
    extern __shared__ char smem[];   // 64 KB fragment-ordered weights

    const int t    = threadIdx.x;
    const int lane = t & 63;
    const int w    = t >> 6;
    const int g    = lane >> 4;
    const int l15  = lane & 15;
    const int coff = g * 8;
    const int bx   = blockIdx.x;

    // ---- B: 64 KB global->LDS async, staged once
#pragma unroll
    for (int i = 0; i < 16; ++i) {
        int off = (i * 256 + t) * 16;
        __builtin_amdgcn_global_load_lds(
            (const __attribute__((address_space(1))) void*)((const char*)Wf + off),
            (__attribute__((address_space(3))) void*)(smem + (i * 256 + (t & ~63)) * 16),
            16, 0, 0);
    }

    float4 P0[8], C0[8], P1[8], C1[8];
    LOADA(0, P0, C0);

    __syncthreads();   // the only barrier: B (and step-0 A) ready

    const char* bs_base = (const char*)smem + lane * 16;

#pragma unroll
    for (int it = 0; it < 4; ++it) {
        // prefetch next step's A into the dead buffer (stays in flight
        // across this step's MFMA loop)
        if (it == 0) LOADA(1, P1, C1);
        if (it == 1) LOADA(2, P0, C0);
        if (it == 2) LOADA(3, P1, C1);

        f32x4 acc[NT];
#pragma unroll
        for (int i = 0; i < NT; ++i) { acc[i][0] = 0.f; acc[i][1] = 0.f; acc[i][2] = 0.f; acc[i][3] = 0.f; }

#pragma unroll
        for (int s = 0; s < 8; ++s) {
            short8 afr;
            if ((it & 1) == 0) afr = (s < 4) ? cvt8(P0[s * 2], P0[s * 2 + 1])
                                             : cvt8(C0[(s - 4) * 2], C0[(s - 4) * 2 + 1]);
            else               afr = (s < 4) ? cvt8(P1[s * 2], P1[s * 2 + 1])
                                             : cvt8(C1[(s - 4) * 2], C1[(s - 4) * 2 + 1]);
#pragma unroll
            for (int tn = 0; tn < NT; ++tn) {
                short8 wfrag = *(const short8*)(bs_base + ((s * NT + tn) << 10));
                acc[tn] = __builtin_amdgcn_mfma_f32_16x16x32_bf16(wfrag, afr, acc[tn], 0, 0, 0);
            }
        }

        // ---- store: lane holds cols (tn*16 + g*4 + r) of row R
        const int R = (bx + it * 512) * 64 + w * 16 + l15;
        const int p = R & (L - 1);
        float* outr = out + (size_t)R * F;
#pragma unroll
        for (int tn = 0; tn < NT; ++tn) {
            int col = tn * 16 + g * 4;
            float4 bb = *(const float4*)(bbar + col);
            float4 v = make_float4(acc[tn][0] + bb.x, acc[tn][1] + bb.y,
                                   acc[tn][2] + bb.z, acc[tn][3] + bb.w);
            if (p == 0) v = *(const float4*)(loc + (size_t)R * F + col);  // out[b,0,:]=loc[b,0,:]
            *(float4*)(outr + col) = v;
        }
    }
}

} // namespace

extern "C" void kernel_launch(void* const* d_in, const int* in_sizes, int n_in,
                              void* d_out, int out_size, void* d_ws, size_t ws_size,
                              hipStream_t stream) {
    const float* loc  = (const float*)d_in[0];
    const float* Wsrc = (const float*)d_in[1];
    // d_in[2] W_dst, d_in[3] attn_l, d_in[4] attn_r cancel (alpha == 1)
    const float* Wres = (const float*)d_in[5];
    const float* bias = (const float*)d_in[6];

    unsigned short* Wf   = (unsigned short*)d_ws;          // 32768 bf16 = 64 KB
    float*          bbar = (float*)((char*)d_ws + 2 * F * F * 2);
    float*          outp = (float*)d_out;

    prep<<<128, 256, 0, stream>>>(Wsrc, Wres, bias, Wf, bbar);

    gat_mfma<<<512, 256, 65536, stream>>>(loc, Wf, bbar, outp);
}